// Round 4
// baseline (37112.247 us; speedup 1.0000x reference)
//
#include <hip/hip_runtime.h>
#include <hip/hip_bf16.h>
#include <math.h>

// Problem dims (fixed by the reference)
namespace {
constexpr int B  = 512;
constexpr int S  = 1024;
constexpr int ID = 64;    // input / output feature dim
constexpr int H  = 512;
constexpr int T  = 256;
constexpr int NKT = 18;   // K-chunks of 32: 16 over h (K=512) + 2 over x/y (K=64)
}

using short8  = __attribute__((ext_vector_type(8))) short;
using float4v = __attribute__((ext_vector_type(4))) float;

// ---- helpers ----------------------------------------------------------------
__device__ inline ushort bfbits(float x) {
    union { __hip_bfloat16 h; ushort u; } cv;
    cv.h = __float2bfloat16(x);   // RNE
    return cv.u;
}
__device__ inline short8 pack8(float4v f0, float4v f1) {
    short8 a;
    a[0]=(short)bfbits(f0[0]); a[1]=(short)bfbits(f0[1]);
    a[2]=(short)bfbits(f0[2]); a[3]=(short)bfbits(f0[3]);
    a[4]=(short)bfbits(f1[0]); a[5]=(short)bfbits(f1[1]);
    a[6]=(short)bfbits(f1[2]); a[7]=(short)bfbits(f1[3]);
    return a;
}
__device__ inline short8 cvt8(const float* __restrict__ p) {
    return pack8(*(const float4v*)p, *(const float4v*)(p + 4));
}

// ---- one-time prep ----------------------------------------------------------
// Zero barrier + bf16 h ping-pong; prefill out/y0 with bl and hA with 0
// (the latter three only needed by the fallback path; cheap).
__global__ __launch_bounds__(256) void init_kernel(float* __restrict__ out,
                                                   float* __restrict__ y0,
                                                   float* __restrict__ hA,
                                                   ushort* __restrict__ hb0,
                                                   ushort* __restrict__ hb1,
                                                   uint* __restrict__ bar,
                                                   const float* __restrict__ bl) {
    const long n_out = (long)B * T * ID;
    const long n_y0  = n_out + (long)B * ID;
    const long n_hA  = n_y0 + (long)B * H;
    const long n_hb  = n_hA + 2L * B * H;     // hb0+hb1 (ushort)
    const long total = n_hb + 64;             // barrier words
    for (long idx = (long)blockIdx.x * 256 + threadIdx.x; idx < total;
         idx += (long)gridDim.x * 256) {
        if (idx < n_out)       out[idx] = bl[idx & (ID - 1)];
        else if (idx < n_y0)   y0[idx - n_out] = bl[(idx - n_out) & (ID - 1)];
        else if (idx < n_hA)   hA[idx - n_y0] = 0.f;
        else if (idx < n_hb) { long k = idx - n_hA;
                               if (k < (long)B * H) hb0[k] = 0; else hb1[k - (long)B * H] = 0; }
        else                   bar[idx - n_hb] = 0u;
    }
}

// Swizzle [Wh | Wi] (fp32) into MFMA-native bf16 B-fragments (see r3 notes).
__global__ __launch_bounds__(256) void prep_swizzle(const float* __restrict__ Wh,
                                                    const float* __restrict__ Wi,
                                                    ushort* __restrict__ Bs) {
    const int t = blockIdx.x * 256 + threadIdx.x;
    constexpr int TOT = 3 * 32 * NKT * 64;
    if (t >= TOT) return;
    const int l   = t & 63;
    int rest      = t >> 6;
    const int kt  = rest % NKT;  rest /= NKT;
    const int jt  = rest & 31;
    const int g   = rest >> 5;
    const int j  = jt * 16 + (l & 15);
    const int kb = kt * 32 + ((l >> 4) << 3);
    ushort v[8];
    if (kt < 16) {
        const float* src = Wh + (long)(g * H + j) * H + kb;
        #pragma unroll
        for (int i = 0; i < 8; ++i) v[i] = bfbits(src[i]);
    } else {
        const float* src = Wi + (long)(g * H + j) * ID + (kb - H);
        #pragma unroll
        for (int i = 0; i < 8; ++i) v[i] = bfbits(src[i]);
    }
    *(short8*)(Bs + (size_t)t * 8) = *(short8*)v;
}

// Swizzle Wl [ID,H] into bf16 B-fragments: frag (ct,kt): lane l elem i =
// Wl[ct*16+(l&15)][kt*32+(l>>4)*8+i].
__global__ __launch_bounds__(256) void prep_wl(const float* __restrict__ Wl,
                                               ushort* __restrict__ Wsl) {
    const int t = blockIdx.x * 256 + threadIdx.x;
    if (t >= 4 * 16 * 64) return;
    const int l  = t & 63;
    const int kt = (t >> 6) & 15;
    const int ct = t >> 10;
    const int jy = ct * 16 + (l & 15);
    const int kc = kt * 32 + ((l >> 4) << 3);
    ushort v[8];
    #pragma unroll
    for (int i = 0; i < 8; ++i) v[i] = bfbits(Wl[(long)jy * H + kc + i]);
    *(short8*)(Wsl + (size_t)t * 8) = *(short8*)v;
}

// ---- grid barrier -----------------------------------------------------------
__device__ __forceinline__ void grid_sync(uint* cnt, uint* gen) {
    __builtin_amdgcn_fence(__ATOMIC_RELEASE, "agent");  // drain + write back my stores
    __syncthreads();
    if (threadIdx.x == 0) {
        uint g = __hip_atomic_load(gen, __ATOMIC_RELAXED, __HIP_MEMORY_SCOPE_AGENT);
        uint a = __hip_atomic_fetch_add(cnt, 1u, __ATOMIC_ACQ_REL, __HIP_MEMORY_SCOPE_AGENT);
        if (a == gridDim.x - 1) {
            __hip_atomic_store(cnt, 0u, __ATOMIC_RELAXED, __HIP_MEMORY_SCOPE_AGENT);
            __hip_atomic_store(gen, g + 1u, __ATOMIC_RELEASE, __HIP_MEMORY_SCOPE_AGENT);
        } else {
            while (__hip_atomic_load(gen, __ATOMIC_RELAXED, __HIP_MEMORY_SCOPE_AGENT) == g)
                __builtin_amdgcn_s_sleep(4);
        }
    }
    __syncthreads();
    __builtin_amdgcn_fence(__ATOMIC_ACQUIRE, "agent"); // invalidate for fresh reads
}

// ---- y projection (redundant per btile; result into private LDS tile) ------
__device__ __forceinline__ void compute_y(
    const ushort* __restrict__ hsrc, const ushort* __restrict__ wl_lds,
    ushort* __restrict__ ytile_w, float* __restrict__ out, int t, bool wout,
    int arow, int kb, int l, int btile, float4v blv)
{
    short8 ha[16];
    #pragma unroll
    for (int kt = 0; kt < 16; ++kt)
        ha[kt] = *(const short8*)(hsrc + (size_t)arow * H + kt * 32 + kb);
    float4v yac[4];
    #pragma unroll
    for (int ct = 0; ct < 4; ++ct) yac[ct] = float4v{0.f, 0.f, 0.f, 0.f};
    #pragma unroll
    for (int ct = 0; ct < 4; ++ct) {
        #pragma unroll
        for (int kt = 0; kt < 16; ++kt) {
            const short8 wb = *(const short8*)(wl_lds + ((size_t)(ct * 16 + kt) * 64 + l) * 8);
            yac[ct] = __builtin_amdgcn_mfma_f32_16x16x32_bf16(ha[kt], wb, yac[ct], 0, 0, 0);
        }
    }
    #pragma unroll
    for (int ct = 0; ct < 4; ++ct) {
        #pragma unroll
        for (int c = 0; c < 4; ++c) {
            const float y = yac[ct][c] + blv[ct];
            const int row = ((l >> 4) << 2) + c;
            ytile_w[row * 80 + ct * 16 + (l & 15)] = bfbits(y);
            if (wout)
                out[((size_t)(btile * 16 + row) * T + t) * ID + ct * 16 + (l & 15)] = y;
        }
    }
}

// ---- THE persistent kernel --------------------------------------------------
// 256 blocks (1/CU) x 256 thr. Wave (block,w): btile = blk&31, jt = (blk>>5)*4+w.
// Weight B-fragments live in registers (216 VGPR); h carried fp32 in registers
// (own outputs) + bf16 in global ping-pong (cross-wave A-operands).
__global__ __launch_bounds__(256, 1) void gru_persistent(
    const float* __restrict__ x, const ushort* __restrict__ Bs,
    const ushort* __restrict__ Wsl, const float* __restrict__ bi,
    const float* __restrict__ bh, const float* __restrict__ bl,
    ushort* __restrict__ hb0, ushort* __restrict__ hb1,
    float* __restrict__ out, uint* __restrict__ bar)
{
    __shared__ ushort wl_lds[4 * 16 * 64 * 8];  // 64 KB swizzled Wl
    __shared__ ushort ytile[4][16][80];         // 20 KB per-wave y scratch (pad 80)

    const int tid = threadIdx.x, w = tid >> 6, l = tid & 63;
    const int bk = blockIdx.x;
    const int btile = bk & 31, jt = ((bk >> 5) << 2) + w;
    const int arow = (btile << 4) + (l & 15);
    const int kb = (l >> 4) << 3;
    const int j = (jt << 4) + (l & 15);
    uint* cnt = bar; uint* gen = bar + 32;

    // stage Wl fragments into LDS
    #pragma unroll
    for (int i = 0; i < 16; ++i) {
        const int idx = tid + i * 256;
        *(short8*)(wl_lds + (size_t)idx * 8) = *(const short8*)(Wsl + (size_t)idx * 8);
    }
    __syncthreads();

    // pin this wave's weight fragments in registers
    short8 wf[3][18];
    #pragma unroll
    for (int g = 0; g < 3; ++g)
        #pragma unroll
        for (int kt = 0; kt < 18; ++kt)
            wf[g][kt] = *(const short8*)(Bs + ((size_t)((g * 32 + jt) * 18 + kt) * 64 + l) * 8);

    const float bir = bi[j] + bh[j];
    const float biz = bi[H + j] + bh[H + j];
    const float bin = bi[2 * H + j];
    const float bhn = bh[2 * H + j];
    float4v blv;
    #pragma unroll
    for (int ct = 0; ct < 4; ++ct) blv[ct] = bl[ct * 16 + (l & 15)];

    float hprev[4] = {0.f, 0.f, 0.f, 0.f};
    const float* xrow = x + (size_t)arow * S * ID;
    float4v xp0 = *(const float4v*)(xrow + kb);
    float4v xp1 = *(const float4v*)(xrow + kb + 4);
    float4v xp2 = *(const float4v*)(xrow + kb + 32);
    float4v xp3 = *(const float4v*)(xrow + kb + 36);

    int cur = 0;
    // ===================== encoder =====================
    for (int t = 0; t < S; ++t) {
        const ushort* hin = cur ? hb1 : hb0;
        ushort*      hout = cur ? hb0 : hb1;
        float4v ar{0.f,0.f,0.f,0.f}, az{0.f,0.f,0.f,0.f};
        float4v anh{0.f,0.f,0.f,0.f}, anx{0.f,0.f,0.f,0.f};
        const short8 a16 = pack8(xp0, xp1), a17 = pack8(xp2, xp3);
        #pragma unroll
        for (int kt = 0; kt < 16; ++kt) {
            const short8 a = *(const short8*)(hin + (size_t)arow * H + kt * 32 + kb);
            ar  = __builtin_amdgcn_mfma_f32_16x16x32_bf16(a, wf[0][kt], ar, 0, 0, 0);
            az  = __builtin_amdgcn_mfma_f32_16x16x32_bf16(a, wf[1][kt], az, 0, 0, 0);
            anh = __builtin_amdgcn_mfma_f32_16x16x32_bf16(a, wf[2][kt], anh, 0, 0, 0);
        }
        ar  = __builtin_amdgcn_mfma_f32_16x16x32_bf16(a16, wf[0][16], ar, 0, 0, 0);
        az  = __builtin_amdgcn_mfma_f32_16x16x32_bf16(a16, wf[1][16], az, 0, 0, 0);
        anx = __builtin_amdgcn_mfma_f32_16x16x32_bf16(a16, wf[2][16], anx, 0, 0, 0);
        ar  = __builtin_amdgcn_mfma_f32_16x16x32_bf16(a17, wf[0][17], ar, 0, 0, 0);
        az  = __builtin_amdgcn_mfma_f32_16x16x32_bf16(a17, wf[1][17], az, 0, 0, 0);
        anx = __builtin_amdgcn_mfma_f32_16x16x32_bf16(a17, wf[2][17], anx, 0, 0, 0);
        if (t + 1 < S) {   // prefetch next x; completes under the barrier's fence
            const float* xr = xrow + (size_t)(t + 1) * ID;
            xp0 = *(const float4v*)(xr + kb);      xp1 = *(const float4v*)(xr + kb + 4);
            xp2 = *(const float4v*)(xr + kb + 32); xp3 = *(const float4v*)(xr + kb + 36);
        }
        #pragma unroll
        for (int c = 0; c < 4; ++c) {
            const float r = 1.f / (1.f + expf(-(ar[c] + bir)));
            const float z = 1.f / (1.f + expf(-(az[c] + biz)));
            const float n = tanhf(anx[c] + bin + r * (anh[c] + bhn));
            const float h = (1.f - z) * n + z * hprev[c];
            hprev[c] = h;
            const int crow = (btile << 4) + ((l >> 4) << 2) + c;
            hout[(size_t)crow * H + j] = bfbits(h);
        }
        grid_sync(cnt, gen);
        cur ^= 1;
    }

    // ===================== y0 (not written to out) =====================
    {
        const ushort* hsrc = cur ? hb1 : hb0;
        compute_y(hsrc, wl_lds, &ytile[w][0][0], out, 0, false, arow, kb, l, btile, blv);
    }

    // ===================== decoder =====================
    for (int t = 0; t < T; ++t) {
        const ushort* hin = cur ? hb1 : hb0;
        ushort*      hout = cur ? hb0 : hb1;
        float4v ar{0.f,0.f,0.f,0.f}, az{0.f,0.f,0.f,0.f};
        float4v anh{0.f,0.f,0.f,0.f}, anx{0.f,0.f,0.f,0.f};
        const short8 a16 = *(const short8*)(&ytile[w][l & 15][kb]);
        const short8 a17 = *(const short8*)(&ytile[w][l & 15][kb + 32]);
        #pragma unroll
        for (int kt = 0; kt < 16; ++kt) {
            const short8 a = *(const short8*)(hin + (size_t)arow * H + kt * 32 + kb);
            ar  = __builtin_amdgcn_mfma_f32_16x16x32_bf16(a, wf[0][kt], ar, 0, 0, 0);
            az  = __builtin_amdgcn_mfma_f32_16x16x32_bf16(a, wf[1][kt], az, 0, 0, 0);
            anh = __builtin_amdgcn_mfma_f32_16x16x32_bf16(a, wf[2][kt], anh, 0, 0, 0);
        }
        ar  = __builtin_amdgcn_mfma_f32_16x16x32_bf16(a16, wf[0][16], ar, 0, 0, 0);
        az  = __builtin_amdgcn_mfma_f32_16x16x32_bf16(a16, wf[1][16], az, 0, 0, 0);
        anx = __builtin_amdgcn_mfma_f32_16x16x32_bf16(a16, wf[2][16], anx, 0, 0, 0);
        ar  = __builtin_amdgcn_mfma_f32_16x16x32_bf16(a17, wf[0][17], ar, 0, 0, 0);
        az  = __builtin_amdgcn_mfma_f32_16x16x32_bf16(a17, wf[1][17], az, 0, 0, 0);
        anx = __builtin_amdgcn_mfma_f32_16x16x32_bf16(a17, wf[2][17], anx, 0, 0, 0);
        #pragma unroll
        for (int c = 0; c < 4; ++c) {
            const float r = 1.f / (1.f + expf(-(ar[c] + bir)));
            const float z = 1.f / (1.f + expf(-(az[c] + biz)));
            const float n = tanhf(anx[c] + bin + r * (anh[c] + bhn));
            const float h = (1.f - z) * n + z * hprev[c];
            hprev[c] = h;
            const int crow = (btile << 4) + ((l >> 4) << 2) + c;
            hout[(size_t)crow * H + j] = bfbits(h);
        }
        grid_sync(cnt, gen);     // h_t visible everywhere
        cur ^= 1;
        const ushort* hnew = cur ? hb1 : hb0;
        compute_y(hnew, wl_lds, &ytile[w][0][0], out, t, (jt == 0), arow, kb, l, btile, blv);
    }
}

// ---- fallback path (round-3 kernels, verbatim) ------------------------------
__global__ __launch_bounds__(256) void gru_step_mfma(
    const float* __restrict__ xin, long xstride,
    const float* __restrict__ h_in, const ushort* __restrict__ Bs,
    const float* __restrict__ bi, const float* __restrict__ bh,
    float* __restrict__ h_out)
{
    const int tid = threadIdx.x;
    const int w = tid >> 6, l = tid & 63;
    const int btile = blockIdx.x & 31;
    const int jt    = ((blockIdx.x >> 5) << 2) + w;
    const int b0 = btile << 4;
    const int arow = b0 + (l & 15);
    const int kb = (l >> 4) << 3;
    float4v acc_r{0,0,0,0}, acc_z{0,0,0,0}, acc_nh{0,0,0,0}, acc_nx{0,0,0,0};
    constexpr size_t GSTEP = (size_t)32 * NKT * 512;
    const ushort* bsw = Bs + (size_t)jt * NKT * 512 + ((size_t)l << 3);
    const float* ah = h_in + (size_t)arow * H + kb;
    #pragma unroll
    for (int kt = 0; kt < 16; ++kt) {
        const short8 a  = cvt8(ah + kt * 32);
        const short8 br = *(const short8*)(bsw + ((size_t)kt << 9));
        const short8 bz = *(const short8*)(bsw + GSTEP + ((size_t)kt << 9));
        const short8 bn = *(const short8*)(bsw + 2 * GSTEP + ((size_t)kt << 9));
        acc_r  = __builtin_amdgcn_mfma_f32_16x16x32_bf16(a, br, acc_r, 0, 0, 0);
        acc_z  = __builtin_amdgcn_mfma_f32_16x16x32_bf16(a, bz, acc_z, 0, 0, 0);
        acc_nh = __builtin_amdgcn_mfma_f32_16x16x32_bf16(a, bn, acc_nh, 0, 0, 0);
    }
    const float* ax = xin + (size_t)arow * xstride + kb;
    #pragma unroll
    for (int kt = 16; kt < 18; ++kt) {
        const short8 a  = cvt8(ax + (kt - 16) * 32);
        const short8 br = *(const short8*)(bsw + ((size_t)kt << 9));
        const short8 bz = *(const short8*)(bsw + GSTEP + ((size_t)kt << 9));
        const short8 bn = *(const short8*)(bsw + 2 * GSTEP + ((size_t)kt << 9));
        acc_r  = __builtin_amdgcn_mfma_f32_16x16x32_bf16(a, br, acc_r, 0, 0, 0);
        acc_z  = __builtin_amdgcn_mfma_f32_16x16x32_bf16(a, bz, acc_z, 0, 0, 0);
        acc_nx = __builtin_amdgcn_mfma_f32_16x16x32_bf16(a, bn, acc_nx, 0, 0, 0);
    }
    const int j = (jt << 4) + (l & 15);
    const float bir = bi[j] + bh[j];
    const float biz = bi[H + j] + bh[H + j];
    const float bin = bi[2 * H + j];
    const float bhn = bh[2 * H + j];
    #pragma unroll
    for (int c = 0; c < 4; ++c) {
        const int b = b0 + ((l >> 4) << 2) + c;
        const float r = 1.f / (1.f + expf(-(acc_r[c] + bir)));
        const float z = 1.f / (1.f + expf(-(acc_z[c] + biz)));
        const float n = tanhf(acc_nx[c] + bin + r * (acc_nh[c] + bhn));
        h_out[(size_t)b * H + j] = (1.f - z) * n + z * h_in[(size_t)b * H + j];
    }
}

__global__ __launch_bounds__(64) void linear_y(
    const float* __restrict__ h, const float* __restrict__ Wl,
    float* __restrict__ dst, int dst_stride)
{
    const int b = blockIdx.x >> 2;
    const int s = blockIdx.x & 3;
    const int i = threadIdx.x;
    const float4* h4 = (const float4*)(h  + (long)b * H + s * 128);
    const float4* w4 = (const float4*)(Wl + (long)i * H + s * 128);
    float acc = 0.f;
    #pragma unroll
    for (int k = 0; k < 32; ++k) {
        const float4 a = h4[k];
        const float4 w = w4[k];
        acc += a.x * w.x + a.y * w.y + a.z * w.z + a.w * w.w;
    }
    atomicAdd(&dst[(long)b * dst_stride + i], acc);
}

extern "C" void kernel_launch(void* const* d_in, const int* in_sizes, int n_in,
                              void* d_out, int out_size, void* d_ws, size_t ws_size,
                              hipStream_t stream) {
    const float* x  = (const float*)d_in[0];
    const float* Wi = (const float*)d_in[1];
    const float* Wh = (const float*)d_in[2];
    const float* bi = (const float*)d_in[3];
    const float* bh = (const float*)d_in[4];
    const float* Wl = (const float*)d_in[5];
    const float* bl = (const float*)d_in[6];
    float* out = (float*)d_out;

    // workspace carve (256B aligned regions)
    uint*   bar = (uint*)d_ws;                               // 256 B
    ushort* hb0 = (ushort*)((char*)d_ws + 256);              // 512 KB
    ushort* hb1 = hb0 + (size_t)B * H;                       // 512 KB
    ushort* Bs  = hb1 + (size_t)B * H;                       // 1.73 MB
    ushort* Wsl = Bs + (size_t)3 * 32 * NKT * 512;           // 64 KB
    float*  hA  = (float*)(Wsl + (size_t)4 * 16 * 512);      // 1 MB (fallback)
    float*  hB  = hA + (size_t)B * H;                        // 1 MB (fallback)
    float*  y0  = hB + (size_t)B * H;                        // 128 KB (fallback)

    init_kernel<<<2048, 256, 0, stream>>>(out, y0, hA, hb0, hb1, bar, bl);
    prep_swizzle<<<(3 * 32 * NKT * 64 + 255) / 256, 256, 0, stream>>>(Wh, Wi, Bs);
    prep_wl<<<(4 * 16 * 64 + 255) / 256, 256, 0, stream>>>(Wl, Wsl);

    // ---- preferred: single persistent cooperative kernel ----
    {
        const float* xa = x; const ushort* Bsa = Bs; const ushort* Wsla = Wsl;
        const float* bia = bi; const float* bha = bh; const float* bla = bl;
        ushort* h0a = hb0; ushort* h1a = hb1; float* outa = out; uint* bara = bar;
        void* args[] = { &xa, &Bsa, &Wsla, &bia, &bha, &bla, &h0a, &h1a, &outa, &bara };
        hipError_t e = hipLaunchCooperativeKernel((const void*)gru_persistent,
                                                  dim3(256), dim3(256), args, 0, stream);
        if (e == hipSuccess) return;
    }

    // ---- fallback: round-3 per-step path ----
    const float* hin = hA; float* hout = hB;
    for (int t = 0; t < S; ++t) {
        gru_step_mfma<<<256, 256, 0, stream>>>(x + (long)t * ID, (long)S * ID,
                                               hin, Bs, bi, bh, hout);
        const float* tmp = hout; hout = (float*)hin; hin = tmp;
    }
    linear_y<<<B * 4, 64, 0, stream>>>(hin, Wl, y0, ID);
    const float* inp = y0; long instride = ID;
    for (int t = 0; t < T; ++t) {
        gru_step_mfma<<<256, 256, 0, stream>>>(inp, instride, hin, Bs, bi, bh, hout);
        const float* tmp = hout; hout = (float*)hin; hin = tmp;
        linear_y<<<B * 4, 64, 0, stream>>>(hin, Wl, out + (long)t * ID, T * ID);
        inp = out + (long)t * ID; instride = T * ID;
    }
}

// Round 5
// 8890.753 us; speedup vs baseline: 4.1743x; 4.1743x over previous
//
#include <hip/hip_runtime.h>
#include <hip/hip_bf16.h>
#include <math.h>

// Problem dims (fixed by the reference)
namespace {
constexpr int B  = 512;
constexpr int S  = 1024;
constexpr int ID = 64;    // input / output feature dim
constexpr int H  = 512;
constexpr int T  = 256;
constexpr int NKT = 18;   // K-chunks of 32: 16 over h (K=512) + 2 over x/y (K=64)
}

using short8  = __attribute__((ext_vector_type(8))) short;
using float4v = __attribute__((ext_vector_type(4))) float;

// ---- helpers ----------------------------------------------------------------
__device__ inline ushort bfbits(float x) {
    union { __hip_bfloat16 h; ushort u; } cv;
    cv.h = __float2bfloat16(x);   // RNE
    return cv.u;
}
__device__ inline short8 pack8(float4v f0, float4v f1) {
    short8 a;
    a[0]=(short)bfbits(f0[0]); a[1]=(short)bfbits(f0[1]);
    a[2]=(short)bfbits(f0[2]); a[3]=(short)bfbits(f0[3]);
    a[4]=(short)bfbits(f1[0]); a[5]=(short)bfbits(f1[1]);
    a[6]=(short)bfbits(f1[2]); a[7]=(short)bfbits(f1[3]);
    return a;
}
__device__ inline short8 cvt8(const float* __restrict__ p) {
    return pack8(*(const float4v*)p, *(const float4v*)(p + 4));
}

// Coherent (cross-XCD) 2-byte store: write-through past L2.
__device__ __forceinline__ void store_h16(ushort* p, float v) {
    const uint b = (uint)bfbits(v);
    asm volatile("global_store_short %0, %1, off sc0 sc1" :: "v"(p), "v"(b) : "memory");
}

// ---- one-time prep ----------------------------------------------------------
__global__ __launch_bounds__(256) void init_kernel(float* __restrict__ out,
                                                   float* __restrict__ y0,
                                                   float* __restrict__ hA,
                                                   ushort* __restrict__ hb0,
                                                   ushort* __restrict__ hb1,
                                                   uint* __restrict__ bar,
                                                   const float* __restrict__ bl) {
    const long n_out = (long)B * T * ID;
    const long n_y0  = n_out + (long)B * ID;
    const long n_hA  = n_y0 + (long)B * H;
    const long n_hb  = n_hA + 2L * B * H;     // hb0+hb1 (ushort)
    const long total = n_hb + 1024;           // barrier words (32 ctr x 128B)
    for (long idx = (long)blockIdx.x * 256 + threadIdx.x; idx < total;
         idx += (long)gridDim.x * 256) {
        if (idx < n_out)       out[idx] = bl[idx & (ID - 1)];
        else if (idx < n_y0)   y0[idx - n_out] = bl[(idx - n_out) & (ID - 1)];
        else if (idx < n_hA)   hA[idx - n_y0] = 0.f;
        else if (idx < n_hb) { long k = idx - n_hA;
                               if (k < (long)B * H) hb0[k] = 0; else hb1[k - (long)B * H] = 0; }
        else                   bar[idx - n_hb] = 0u;
    }
}

// Swizzle [Wh | Wi] (fp32) into MFMA-native bf16 B-fragments (see r3 notes).
__global__ __launch_bounds__(256) void prep_swizzle(const float* __restrict__ Wh,
                                                    const float* __restrict__ Wi,
                                                    ushort* __restrict__ Bs) {
    const int t = blockIdx.x * 256 + threadIdx.x;
    constexpr int TOT = 3 * 32 * NKT * 64;
    if (t >= TOT) return;
    const int l   = t & 63;
    int rest      = t >> 6;
    const int kt  = rest % NKT;  rest /= NKT;
    const int jt  = rest & 31;
    const int g   = rest >> 5;
    const int j  = jt * 16 + (l & 15);
    const int kb = kt * 32 + ((l >> 4) << 3);
    ushort v[8];
    if (kt < 16) {
        const float* src = Wh + (long)(g * H + j) * H + kb;
        #pragma unroll
        for (int i = 0; i < 8; ++i) v[i] = bfbits(src[i]);
    } else {
        const float* src = Wi + (long)(g * H + j) * ID + (kb - H);
        #pragma unroll
        for (int i = 0; i < 8; ++i) v[i] = bfbits(src[i]);
    }
    *(short8*)(Bs + (size_t)t * 8) = *(short8*)v;
}

// Swizzle Wl [ID,H] into bf16 B-fragments.
__global__ __launch_bounds__(256) void prep_wl(const float* __restrict__ Wl,
                                               ushort* __restrict__ Wsl) {
    const int t = blockIdx.x * 256 + threadIdx.x;
    if (t >= 4 * 16 * 64) return;
    const int l  = t & 63;
    const int kt = (t >> 6) & 15;
    const int ct = t >> 10;
    const int jy = ct * 16 + (l & 15);
    const int kc = kt * 32 + ((l >> 4) << 3);
    ushort v[8];
    #pragma unroll
    for (int i = 0; i < 8; ++i) v[i] = bfbits(Wl[(long)jy * H + kc + i]);
    *(short8*)(Wsl + (size_t)t * 8) = *(short8*)v;
}

// ---- per-btile group sync (8 blocks, monotonic counter, no cache fences) ----
__device__ __forceinline__ void group_sync(uint* cnt, uint target) {
    asm volatile("s_waitcnt vmcnt(0)" ::: "memory");  // my h-stores are at the coherence point
    __builtin_amdgcn_sched_barrier(0);
    __syncthreads();                                  // every wave drained
    if (threadIdx.x == 0) {
        __hip_atomic_fetch_add(cnt, 1u, __ATOMIC_RELAXED, __HIP_MEMORY_SCOPE_AGENT);
        while (__hip_atomic_load(cnt, __ATOMIC_RELAXED, __HIP_MEMORY_SCOPE_AGENT) < target)
            __builtin_amdgcn_s_sleep(1);
    }
    __syncthreads();
}

// ---- y projection (redundant per btile; result into private LDS tile) ------
__device__ __forceinline__ void compute_y(
    const ushort* __restrict__ hsrc, const ushort* __restrict__ wl_lds,
    ushort* __restrict__ ytile_w, float* __restrict__ out, int t, bool wout,
    int arow, int kb, int l, int btile, float4v blv)
{
    union HS { unsigned long long u[2]; short8 s; };
    HS ha[16];
    const unsigned long long* hp = (const unsigned long long*)(hsrc + (size_t)arow * H);
    #pragma unroll
    for (int kt = 0; kt < 16; ++kt) {
        const int q = (kt * 32 + kb) >> 2;
        ha[kt].u[0] = __hip_atomic_load(hp + q,     __ATOMIC_RELAXED, __HIP_MEMORY_SCOPE_AGENT);
        ha[kt].u[1] = __hip_atomic_load(hp + q + 1, __ATOMIC_RELAXED, __HIP_MEMORY_SCOPE_AGENT);
    }
    float4v yac[4];
    #pragma unroll
    for (int ct = 0; ct < 4; ++ct) yac[ct] = float4v{0.f, 0.f, 0.f, 0.f};
    #pragma unroll
    for (int ct = 0; ct < 4; ++ct) {
        #pragma unroll
        for (int kt = 0; kt < 16; ++kt) {
            const short8 wb = *(const short8*)(wl_lds + ((size_t)(ct * 16 + kt) * 64 + l) * 8);
            yac[ct] = __builtin_amdgcn_mfma_f32_16x16x32_bf16(ha[kt].s, wb, yac[ct], 0, 0, 0);
        }
    }
    #pragma unroll
    for (int ct = 0; ct < 4; ++ct) {
        #pragma unroll
        for (int c = 0; c < 4; ++c) {
            const float y = yac[ct][c] + blv[ct];
            const int row = ((l >> 4) << 2) + c;
            ytile_w[row * 80 + ct * 16 + (l & 15)] = bfbits(y);
            if (wout)
                out[((size_t)(btile * 16 + row) * T + t) * ID + ct * 16 + (l & 15)] = y;
        }
    }
}

// ---- THE persistent kernel --------------------------------------------------
__global__ __launch_bounds__(256, 1) void gru_persistent(
    const float* __restrict__ x, const ushort* __restrict__ Bs,
    const ushort* __restrict__ Wsl, const float* __restrict__ bi,
    const float* __restrict__ bh, const float* __restrict__ bl,
    ushort* __restrict__ hb0, ushort* __restrict__ hb1,
    float* __restrict__ out, uint* __restrict__ bar)
{
    __shared__ ushort wl_lds[4 * 16 * 64 * 8];  // 64 KB swizzled Wl
    __shared__ ushort ytile[4][16][80];         // 10 KB per-wave y scratch (pad 80)

    const int tid = threadIdx.x, w = tid >> 6, l = tid & 63;
    const int bk = blockIdx.x;
    const int btile = bk & 31, jt = ((bk >> 5) << 2) + w;
    const int arow = (btile << 4) + (l & 15);
    const int kb = (l >> 4) << 3;
    const int j = (jt << 4) + (l & 15);
    uint* cnt = bar + btile * 32;               // 128B-spaced per-btile counter

    // stage Wl fragments into LDS
    #pragma unroll
    for (int i = 0; i < 16; ++i) {
        const int idx = tid + i * 256;
        *(short8*)(wl_lds + (size_t)idx * 8) = *(const short8*)(Wsl + (size_t)idx * 8);
    }
    __syncthreads();

    // pin this wave's weight fragments in registers (opaque => no remat)
    short8 wf[3][18];
    #pragma unroll
    for (int g = 0; g < 3; ++g)
        #pragma unroll
        for (int kt = 0; kt < 18; ++kt) {
            wf[g][kt] = *(const short8*)(Bs + ((size_t)((g * 32 + jt) * 18 + kt) * 64 + l) * 8);
            asm volatile("" : "+v"(wf[g][kt]));
        }

    const float bir = bi[j] + bh[j];
    const float biz = bi[H + j] + bh[H + j];
    const float bin = bi[2 * H + j];
    const float bhn = bh[2 * H + j];
    float4v blv;
    #pragma unroll
    for (int ct = 0; ct < 4; ++ct) blv[ct] = bl[ct * 16 + (l & 15)];

    float hprev[4] = {0.f, 0.f, 0.f, 0.f};
    const float* xrow = x + (size_t)arow * S * ID;
    float4v xp0 = *(const float4v*)(xrow + kb);
    float4v xp1 = *(const float4v*)(xrow + kb + 4);
    float4v xp2 = *(const float4v*)(xrow + kb + 32);
    float4v xp3 = *(const float4v*)(xrow + kb + 36);

    union HS { unsigned long long u[2]; short8 s; };
    int cur = 0;
    // ===================== encoder =====================
    for (int t = 0; t < S; ++t) {
        const ushort* hin = cur ? hb1 : hb0;
        ushort*      hout = cur ? hb0 : hb1;
        // coherent h loads, all issued up front
        HS hv[16];
        const unsigned long long* hp = (const unsigned long long*)(hin + (size_t)arow * H);
        #pragma unroll
        for (int kt = 0; kt < 16; ++kt) {
            const int q = (kt * 32 + kb) >> 2;
            hv[kt].u[0] = __hip_atomic_load(hp + q,     __ATOMIC_RELAXED, __HIP_MEMORY_SCOPE_AGENT);
            hv[kt].u[1] = __hip_atomic_load(hp + q + 1, __ATOMIC_RELAXED, __HIP_MEMORY_SCOPE_AGENT);
        }
        float4v ar{0.f,0.f,0.f,0.f}, az{0.f,0.f,0.f,0.f};
        float4v anh{0.f,0.f,0.f,0.f}, anx{0.f,0.f,0.f,0.f};
        const short8 a16 = pack8(xp0, xp1), a17 = pack8(xp2, xp3);
        #pragma unroll
        for (int kt = 0; kt < 16; ++kt) {
            ar  = __builtin_amdgcn_mfma_f32_16x16x32_bf16(hv[kt].s, wf[0][kt], ar, 0, 0, 0);
            az  = __builtin_amdgcn_mfma_f32_16x16x32_bf16(hv[kt].s, wf[1][kt], az, 0, 0, 0);
            anh = __builtin_amdgcn_mfma_f32_16x16x32_bf16(hv[kt].s, wf[2][kt], anh, 0, 0, 0);
        }
        ar  = __builtin_amdgcn_mfma_f32_16x16x32_bf16(a16, wf[0][16], ar, 0, 0, 0);
        az  = __builtin_amdgcn_mfma_f32_16x16x32_bf16(a16, wf[1][16], az, 0, 0, 0);
        anx = __builtin_amdgcn_mfma_f32_16x16x32_bf16(a16, wf[2][16], anx, 0, 0, 0);
        ar  = __builtin_amdgcn_mfma_f32_16x16x32_bf16(a17, wf[0][17], ar, 0, 0, 0);
        az  = __builtin_amdgcn_mfma_f32_16x16x32_bf16(a17, wf[1][17], az, 0, 0, 0);
        anx = __builtin_amdgcn_mfma_f32_16x16x32_bf16(a17, wf[2][17], anx, 0, 0, 0);
        if (t + 1 < S) {   // prefetch next x
            const float* xr = xrow + (size_t)(t + 1) * ID;
            xp0 = *(const float4v*)(xr + kb);      xp1 = *(const float4v*)(xr + kb + 4);
            xp2 = *(const float4v*)(xr + kb + 32); xp3 = *(const float4v*)(xr + kb + 36);
        }
        #pragma unroll
        for (int c = 0; c < 4; ++c) {
            const float r = 1.f / (1.f + expf(-(ar[c] + bir)));
            const float z = 1.f / (1.f + expf(-(az[c] + biz)));
            const float n = tanhf(anx[c] + bin + r * (anh[c] + bhn));
            const float h = (1.f - z) * n + z * hprev[c];
            hprev[c] = h;
            const int crow = (btile << 4) + ((l >> 4) << 2) + c;
            store_h16(hout + (size_t)crow * H + j, h);
        }
        group_sync(cnt, 8u * (uint)(t + 1));
        cur ^= 1;
    }

    // ===================== y0 (not written to out) =====================
    {
        const ushort* hsrc = cur ? hb1 : hb0;
        compute_y(hsrc, wl_lds, &ytile[w][0][0], out, 0, false, arow, kb, l, btile, blv);
    }

    // ===================== decoder =====================
    for (int t = 0; t < T; ++t) {
        const ushort* hin = cur ? hb1 : hb0;
        ushort*      hout = cur ? hb0 : hb1;
        HS hv[16];
        const unsigned long long* hp = (const unsigned long long*)(hin + (size_t)arow * H);
        #pragma unroll
        for (int kt = 0; kt < 16; ++kt) {
            const int q = (kt * 32 + kb) >> 2;
            hv[kt].u[0] = __hip_atomic_load(hp + q,     __ATOMIC_RELAXED, __HIP_MEMORY_SCOPE_AGENT);
            hv[kt].u[1] = __hip_atomic_load(hp + q + 1, __ATOMIC_RELAXED, __HIP_MEMORY_SCOPE_AGENT);
        }
        float4v ar{0.f,0.f,0.f,0.f}, az{0.f,0.f,0.f,0.f};
        float4v anh{0.f,0.f,0.f,0.f}, anx{0.f,0.f,0.f,0.f};
        const short8 a16 = *(const short8*)(&ytile[w][l & 15][kb]);
        const short8 a17 = *(const short8*)(&ytile[w][l & 15][kb + 32]);
        #pragma unroll
        for (int kt = 0; kt < 16; ++kt) {
            ar  = __builtin_amdgcn_mfma_f32_16x16x32_bf16(hv[kt].s, wf[0][kt], ar, 0, 0, 0);
            az  = __builtin_amdgcn_mfma_f32_16x16x32_bf16(hv[kt].s, wf[1][kt], az, 0, 0, 0);
            anh = __builtin_amdgcn_mfma_f32_16x16x32_bf16(hv[kt].s, wf[2][kt], anh, 0, 0, 0);
        }
        ar  = __builtin_amdgcn_mfma_f32_16x16x32_bf16(a16, wf[0][16], ar, 0, 0, 0);
        az  = __builtin_amdgcn_mfma_f32_16x16x32_bf16(a16, wf[1][16], az, 0, 0, 0);
        anx = __builtin_amdgcn_mfma_f32_16x16x32_bf16(a16, wf[2][16], anx, 0, 0, 0);
        ar  = __builtin_amdgcn_mfma_f32_16x16x32_bf16(a17, wf[0][17], ar, 0, 0, 0);
        az  = __builtin_amdgcn_mfma_f32_16x16x32_bf16(a17, wf[1][17], az, 0, 0, 0);
        anx = __builtin_amdgcn_mfma_f32_16x16x32_bf16(a17, wf[2][17], anx, 0, 0, 0);
        #pragma unroll
        for (int c = 0; c < 4; ++c) {
            const float r = 1.f / (1.f + expf(-(ar[c] + bir)));
            const float z = 1.f / (1.f + expf(-(az[c] + biz)));
            const float n = tanhf(anx[c] + bin + r * (anh[c] + bhn));
            const float h = (1.f - z) * n + z * hprev[c];
            hprev[c] = h;
            const int crow = (btile << 4) + ((l >> 4) << 2) + c;
            store_h16(hout + (size_t)crow * H + j, h);
        }
        group_sync(cnt, 8u * (uint)(S + t + 1));
        cur ^= 1;
        const ushort* hnew = cur ? hb1 : hb0;
        compute_y(hnew, wl_lds, &ytile[w][0][0], out, t, (jt == 0), arow, kb, l, btile, blv);
    }
}

// ---- fallback path (round-3 kernels, verbatim) ------------------------------
__global__ __launch_bounds__(256) void gru_step_mfma(
    const float* __restrict__ xin, long xstride,
    const float* __restrict__ h_in, const ushort* __restrict__ Bs,
    const float* __restrict__ bi, const float* __restrict__ bh,
    float* __restrict__ h_out)
{
    const int tid = threadIdx.x;
    const int w = tid >> 6, l = tid & 63;
    const int btile = blockIdx.x & 31;
    const int jt    = ((blockIdx.x >> 5) << 2) + w;
    const int b0 = btile << 4;
    const int arow = b0 + (l & 15);
    const int kb = (l >> 4) << 3;
    float4v acc_r{0,0,0,0}, acc_z{0,0,0,0}, acc_nh{0,0,0,0}, acc_nx{0,0,0,0};
    constexpr size_t GSTEP = (size_t)32 * NKT * 512;
    const ushort* bsw = Bs + (size_t)jt * NKT * 512 + ((size_t)l << 3);
    const float* ah = h_in + (size_t)arow * H + kb;
    #pragma unroll
    for (int kt = 0; kt < 16; ++kt) {
        const short8 a  = cvt8(ah + kt * 32);
        const short8 br = *(const short8*)(bsw + ((size_t)kt << 9));
        const short8 bz = *(const short8*)(bsw + GSTEP + ((size_t)kt << 9));
        const short8 bn = *(const short8*)(bsw + 2 * GSTEP + ((size_t)kt << 9));
        acc_r  = __builtin_amdgcn_mfma_f32_16x16x32_bf16(a, br, acc_r, 0, 0, 0);
        acc_z  = __builtin_amdgcn_mfma_f32_16x16x32_bf16(a, bz, acc_z, 0, 0, 0);
        acc_nh = __builtin_amdgcn_mfma_f32_16x16x32_bf16(a, bn, acc_nh, 0, 0, 0);
    }
    const float* ax = xin + (size_t)arow * xstride + kb;
    #pragma unroll
    for (int kt = 16; kt < 18; ++kt) {
        const short8 a  = cvt8(ax + (kt - 16) * 32);
        const short8 br = *(const short8*)(bsw + ((size_t)kt << 9));
        const short8 bz = *(const short8*)(bsw + GSTEP + ((size_t)kt << 9));
        const short8 bn = *(const short8*)(bsw + 2 * GSTEP + ((size_t)kt << 9));
        acc_r  = __builtin_amdgcn_mfma_f32_16x16x32_bf16(a, br, acc_r, 0, 0, 0);
        acc_z  = __builtin_amdgcn_mfma_f32_16x16x32_bf16(a, bz, acc_z, 0, 0, 0);
        acc_nx = __builtin_amdgcn_mfma_f32_16x16x32_bf16(a, bn, acc_nx, 0, 0, 0);
    }
    const int j = (jt << 4) + (l & 15);
    const float bir = bi[j] + bh[j];
    const float biz = bi[H + j] + bh[H + j];
    const float bin = bi[2 * H + j];
    const float bhn = bh[2 * H + j];
    #pragma unroll
    for (int c = 0; c < 4; ++c) {
        const int b = b0 + ((l >> 4) << 2) + c;
        const float r = 1.f / (1.f + expf(-(acc_r[c] + bir)));
        const float z = 1.f / (1.f + expf(-(acc_z[c] + biz)));
        const float n = tanhf(acc_nx[c] + bin + r * (acc_nh[c] + bhn));
        h_out[(size_t)b * H + j] = (1.f - z) * n + z * h_in[(size_t)b * H + j];
    }
}

__global__ __launch_bounds__(64) void linear_y(
    const float* __restrict__ h, const float* __restrict__ Wl,
    float* __restrict__ dst, int dst_stride)
{
    const int b = blockIdx.x >> 2;
    const int s = blockIdx.x & 3;
    const int i = threadIdx.x;
    const float4* h4 = (const float4*)(h  + (long)b * H + s * 128);
    const float4* w4 = (const float4*)(Wl + (long)i * H + s * 128);
    float acc = 0.f;
    #pragma unroll
    for (int k = 0; k < 32; ++k) {
        const float4 a = h4[k];
        const float4 w = w4[k];
        acc += a.x * w.x + a.y * w.y + a.z * w.z + a.w * w.w;
    }
    atomicAdd(&dst[(long)b * dst_stride + i], acc);
}

extern "C" void kernel_launch(void* const* d_in, const int* in_sizes, int n_in,
                              void* d_out, int out_size, void* d_ws, size_t ws_size,
                              hipStream_t stream) {
    const float* x  = (const float*)d_in[0];
    const float* Wi = (const float*)d_in[1];
    const float* Wh = (const float*)d_in[2];
    const float* bi = (const float*)d_in[3];
    const float* bh = (const float*)d_in[4];
    const float* Wl = (const float*)d_in[5];
    const float* bl = (const float*)d_in[6];
    float* out = (float*)d_out;

    // workspace carve
    uint*   bar = (uint*)d_ws;                               // 4 KB (32 ctr x 128B)
    ushort* hb0 = (ushort*)((char*)d_ws + 4096);             // 512 KB
    ushort* hb1 = hb0 + (size_t)B * H;                       // 512 KB
    ushort* Bs  = hb1 + (size_t)B * H;                       // 1.73 MB
    ushort* Wsl = Bs + (size_t)3 * 32 * NKT * 512;           // 64 KB
    float*  hA  = (float*)(Wsl + (size_t)4 * 16 * 512);      // 1 MB (fallback)
    float*  hB  = hA + (size_t)B * H;                        // 1 MB (fallback)
    float*  y0  = hB + (size_t)B * H;                        // 128 KB (fallback)

    init_kernel<<<2048, 256, 0, stream>>>(out, y0, hA, hb0, hb1, bar, bl);
    prep_swizzle<<<(3 * 32 * NKT * 64 + 255) / 256, 256, 0, stream>>>(Wh, Wi, Bs);
    prep_wl<<<(4 * 16 * 64 + 255) / 256, 256, 0, stream>>>(Wl, Wsl);

    // ---- preferred: single persistent cooperative kernel ----
    {
        const float* xa = x; const ushort* Bsa = Bs; const ushort* Wsla = Wsl;
        const float* bia = bi; const float* bha = bh; const float* bla = bl;
        ushort* h0a = hb0; ushort* h1a = hb1; float* outa = out; uint* bara = bar;
        void* args[] = { &xa, &Bsa, &Wsla, &bia, &bha, &bla, &h0a, &h1a, &outa, &bara };
        hipError_t e = hipLaunchCooperativeKernel((const void*)gru_persistent,
                                                  dim3(256), dim3(256), args, 0, stream);
        if (e == hipSuccess) return;
    }

    // ---- fallback: round-3 per-step path ----
    const float* hin = hA; float* hout = hB;
    for (int t = 0; t < S; ++t) {
        gru_step_mfma<<<256, 256, 0, stream>>>(x + (long)t * ID, (long)S * ID,
                                               hin, Bs, bi, bh, hout);
        const float* tmp = hout; hout = (float*)hin; hin = tmp;
    }
    linear_y<<<B * 4, 64, 0, stream>>>(hin, Wl, y0, ID);
    const float* inp = y0; long instride = ID;
    for (int t = 0; t < T; ++t) {
        gru_step_mfma<<<256, 256, 0, stream>>>(inp, instride, hin, Bs, bi, bh, hout);
        const float* tmp = hout; hout = (float*)hin; hin = tmp;
        linear_y<<<B * 4, 64, 0, stream>>>(hin, Wl, out + (long)t * ID, T * ID);
        inp = out + (long)t * ID; instride = T * ID;
    }
}